// Round 1
// baseline (7093.566 us; speedup 1.0000x reference)
//
#include <hip/hip_runtime.h>
#include <math.h>

#define HDIM 2048
#define G4   (4 * HDIM)   // 8192 gate rows

// ---------------------------------------------------------------------------
// prep: b_sum = b_ih + b_hh ; c = 0
// ---------------------------------------------------------------------------
__global__ __launch_bounds__(256) void prep_small(const float* __restrict__ bih,
                                                  const float* __restrict__ bhh,
                                                  float* __restrict__ bsum,
                                                  float* __restrict__ c) {
    int i = blockIdx.x * blockDim.x + threadIdx.x;
    if (i < G4) bsum[i] = bih[i] + bhh[i];
    if (i < HDIM) c[i] = 0.0f;
}

// ---------------------------------------------------------------------------
// prep: W_sum = W_ih + W_hh   (8192 x 2048 fp32, float4 grid-stride)
// ---------------------------------------------------------------------------
__global__ __launch_bounds__(256) void prep_wsum(const float* __restrict__ Wih,
                                                 const float* __restrict__ Whh,
                                                 float* __restrict__ Wsum) {
    const int n4 = (G4 * HDIM) / 4;  // 4,194,304 float4
    int idx = blockIdx.x * blockDim.x + threadIdx.x;
    int stride = gridDim.x * blockDim.x;
    const float4* a = (const float4*)Wih;
    const float4* b = (const float4*)Whh;
    float4* o = (float4*)Wsum;
    for (int i = idx; i < n4; i += stride) {
        float4 av = a[i], bv = b[i];
        o[i] = make_float4(av.x + bv.x, av.y + bv.y, av.z + bv.z, av.w + bv.w);
    }
}

// ---------------------------------------------------------------------------
// One LSTM time step.
//   gates = x @ W.T (+ x @ W2.T if W2) + bsum       (rows q*H + j)
//   c_new = sig(f)*c + sig(i)*tanh(g);  h = sig(o)*tanh(c_new)
// Grid: 256 blocks x 256 threads. Block b owns h-elements [8b, 8b+8).
// Wave q (of 4) computes gate q for those 8 rows. Lanes stride float4-
// coalesced over the 2048 columns; shuffle-reduce per row.
// ---------------------------------------------------------------------------
__global__ __launch_bounds__(256) void lstm_step(const float* __restrict__ x,
                                                 const float* __restrict__ W,
                                                 const float* __restrict__ W2,
                                                 const float* __restrict__ bsum,
                                                 float* __restrict__ c,
                                                 float* __restrict__ h_out) {
    __shared__ float gates[4][8];

    const int tid  = threadIdx.x;
    const int wave = tid >> 6;   // 0..3 == gate index q (i,f,g,o)
    const int lane = tid & 63;
    const int j0   = blockIdx.x * 8;

    // Load x: float4 index lane + 64k  -> fully coalesced, covers 2048 cols.
    float4 xv[8];
    const float4* xp = (const float4*)x;
#pragma unroll
    for (int k = 0; k < 8; ++k) xv[k] = xp[lane + 64 * k];

    float acc[8];
#pragma unroll
    for (int j8 = 0; j8 < 8; ++j8) {
        const int R = wave * HDIM + j0 + j8;
        const float4* wr = (const float4*)(W + (size_t)R * HDIM);
        float a = 0.0f;
#pragma unroll
        for (int k = 0; k < 8; ++k) {
            float4 wv = wr[lane + 64 * k];
            a += wv.x * xv[k].x + wv.y * xv[k].y + wv.z * xv[k].z + wv.w * xv[k].w;
        }
        if (W2) {
            const float4* wr2 = (const float4*)(W2 + (size_t)R * HDIM);
#pragma unroll
            for (int k = 0; k < 8; ++k) {
                float4 wv = wr2[lane + 64 * k];
                a += wv.x * xv[k].x + wv.y * xv[k].y + wv.z * xv[k].z + wv.w * xv[k].w;
            }
        }
        acc[j8] = a;
    }

    // Reduce each row partial across the 64 lanes.
#pragma unroll
    for (int j8 = 0; j8 < 8; ++j8) {
        float a = acc[j8];
#pragma unroll
        for (int off = 32; off > 0; off >>= 1) a += __shfl_down(a, off, 64);
        if (lane == 0) gates[wave][j8] = a + bsum[wave * HDIM + j0 + j8];
    }
    __syncthreads();

    // Block-local pointwise LSTM update for this block's 8 h-elements.
    if (tid < 8) {
        const int j = j0 + tid;
        const float gi = gates[0][tid];
        const float gf = gates[1][tid];
        const float gg = gates[2][tid];
        const float go = gates[3][tid];
        const float si = 1.0f / (1.0f + expf(-gi));
        const float sf = 1.0f / (1.0f + expf(-gf));
        const float so = 1.0f / (1.0f + expf(-go));
        const float tg = tanhf(gg);
        const float cn = sf * c[j] + si * tg;
        c[j]     = cn;
        h_out[j] = so * tanhf(cn);
    }
}

// ---------------------------------------------------------------------------
extern "C" void kernel_launch(void* const* d_in, const int* in_sizes, int n_in,
                              void* d_out, int out_size, void* d_ws, size_t ws_size,
                              hipStream_t stream) {
    const float* X   = (const float*)d_in[0];
    const float* Wih = (const float*)d_in[1];
    const float* Whh = (const float*)d_in[2];
    const float* bih = (const float*)d_in[3];
    const float* bhh = (const float*)d_in[4];
    float* out = (float*)d_out;

    const int T = out_size / HDIM;  // 512

    // Workspace layout: [W_sum (67.1 MB)][b_sum (32 KB)][c (8 KB)]
    const size_t wsum_bytes = (size_t)G4 * HDIM * sizeof(float);
    const size_t need = wsum_bytes + (size_t)G4 * sizeof(float) + (size_t)HDIM * sizeof(float);
    char* ws = (char*)d_ws;

    float *Wsum, *bsum, *c;
    const bool have_wsum = (ws_size >= need);
    if (have_wsum) {
        Wsum = (float*)ws;
        bsum = (float*)(ws + wsum_bytes);
        c    = bsum + G4;
    } else {
        Wsum = nullptr;
        bsum = (float*)ws;
        c    = bsum + G4;
    }

    prep_small<<<(G4 + 255) / 256, 256, 0, stream>>>(bih, bhh, bsum, c);
    if (have_wsum)
        prep_wsum<<<2048, 256, 0, stream>>>(Wih, Whh, Wsum);

    // t = 0: gates = X @ W_ih.T + b_sum   (h0 = 0)
    lstm_step<<<256, 256, 0, stream>>>(X, Wih, nullptr, bsum, c, out);

    // t >= 1: gates = h_{t-1} @ W_sum.T + b_sum  (feedback: x == h)
    for (int t = 1; t < T; ++t) {
        const float* hprev = out + (size_t)(t - 1) * HDIM;
        float* hnext = out + (size_t)t * HDIM;
        if (have_wsum)
            lstm_step<<<256, 256, 0, stream>>>(hprev, Wsum, nullptr, bsum, c, hnext);
        else
            lstm_step<<<256, 256, 0, stream>>>(hprev, Wih, Whh, bsum, c, hnext);
    }
}

// Round 2
// 3393.644 us; speedup vs baseline: 2.0903x; 2.0903x over previous
//
#include <hip/hip_runtime.h>
#include <hip/hip_fp16.h>
#include <math.h>

#define HDIM 2048
#define G4   (4 * HDIM)   // 8192 gate rows

// ---------------------------------------------------------------------------
// prep: b_sum = b_ih + b_hh ; c = 0
// ---------------------------------------------------------------------------
__global__ __launch_bounds__(256) void prep_small(const float* __restrict__ bih,
                                                  const float* __restrict__ bhh,
                                                  float* __restrict__ bsum,
                                                  float* __restrict__ c) {
    int i = blockIdx.x * blockDim.x + threadIdx.x;
    if (i < G4) bsum[i] = bih[i] + bhh[i];
    if (i < HDIM) c[i] = 0.0f;
}

// ---------------------------------------------------------------------------
// prep: W_sum = fp16(W_ih + W_hh)   (8192 x 2048, 8 elements per thread)
// ---------------------------------------------------------------------------
__global__ __launch_bounds__(256) void prep_wsum_h(const float* __restrict__ Wih,
                                                   const float* __restrict__ Whh,
                                                   __half* __restrict__ Wsum) {
    const int n8 = (G4 * HDIM) / 8;  // 2,097,152 groups of 8
    int idx = blockIdx.x * blockDim.x + threadIdx.x;
    int stride = gridDim.x * blockDim.x;
    const float4* a = (const float4*)Wih;
    const float4* b = (const float4*)Whh;
    for (int i = idx; i < n8; i += stride) {
        float4 a0 = a[2 * i], a1 = a[2 * i + 1];
        float4 b0 = b[2 * i], b1 = b[2 * i + 1];
        __half h[8];
        h[0] = __float2half(a0.x + b0.x);
        h[1] = __float2half(a0.y + b0.y);
        h[2] = __float2half(a0.z + b0.z);
        h[3] = __float2half(a0.w + b0.w);
        h[4] = __float2half(a1.x + b1.x);
        h[5] = __float2half(a1.y + b1.y);
        h[6] = __float2half(a1.z + b1.z);
        h[7] = __float2half(a1.w + b1.w);
        ((uint4*)Wsum)[i] = *(const uint4*)h;
    }
}

// ---------------------------------------------------------------------------
// fp32-weight step (used for t=0 with W_ih, and as fallback).
// Grid: 256 blocks x 256 threads; wave q = gate q; 8 rows per block.
// ---------------------------------------------------------------------------
__global__ __launch_bounds__(256) void lstm_step_f32(const float* __restrict__ x,
                                                     const float* __restrict__ W,
                                                     const float* __restrict__ W2,
                                                     const float* __restrict__ bsum,
                                                     float* __restrict__ c,
                                                     float* __restrict__ h_out) {
    __shared__ float gates[4][8];
    const int tid  = threadIdx.x;
    const int wave = tid >> 6;
    const int lane = tid & 63;
    const int j0   = blockIdx.x * 8;

    float4 xv[8];
    const float4* xp = (const float4*)x;
#pragma unroll
    for (int k = 0; k < 8; ++k) xv[k] = xp[lane + 64 * k];

    float acc[8];
#pragma unroll
    for (int j8 = 0; j8 < 8; ++j8) {
        const int R = wave * HDIM + j0 + j8;
        const float4* wr = (const float4*)(W + (size_t)R * HDIM);
        float a = 0.0f;
#pragma unroll
        for (int k = 0; k < 8; ++k) {
            float4 wv = wr[lane + 64 * k];
            a += wv.x * xv[k].x + wv.y * xv[k].y + wv.z * xv[k].z + wv.w * xv[k].w;
        }
        if (W2) {
            const float4* wr2 = (const float4*)(W2 + (size_t)R * HDIM);
#pragma unroll
            for (int k = 0; k < 8; ++k) {
                float4 wv = wr2[lane + 64 * k];
                a += wv.x * xv[k].x + wv.y * xv[k].y + wv.z * xv[k].z + wv.w * xv[k].w;
            }
        }
        acc[j8] = a;
    }

#pragma unroll
    for (int j8 = 0; j8 < 8; ++j8) {
        float a = acc[j8];
#pragma unroll
        for (int off = 32; off > 0; off >>= 1) a += __shfl_down(a, off, 64);
        if (lane == 0) gates[wave][j8] = a + bsum[wave * HDIM + j0 + j8];
    }
    __syncthreads();

    if (tid < 8) {
        const int j = j0 + tid;
        const float si = 1.0f / (1.0f + expf(-gates[0][tid]));
        const float sf = 1.0f / (1.0f + expf(-gates[1][tid]));
        const float so = 1.0f / (1.0f + expf(-gates[3][tid]));
        const float tg = tanhf(gates[2][tid]);
        const float cn = sf * c[j] + si * tg;
        c[j]     = cn;
        h_out[j] = so * tanhf(cn);
    }
}

// ---------------------------------------------------------------------------
// fp16-weight step: gates = x @ Wh.T + bsum (fp32 x, fp32 accumulate).
// Lane covers columns k*512 + lane*8 + {0..7}, k = 0..3; one uint4 (8 fp16)
// per (row, k) — fully coalesced 1 KB per wave-instruction.
// ---------------------------------------------------------------------------
__global__ __launch_bounds__(256) void lstm_step_h(const float* __restrict__ x,
                                                   const __half* __restrict__ W,
                                                   const float* __restrict__ bsum,
                                                   float* __restrict__ c,
                                                   float* __restrict__ h_out) {
    __shared__ float gates[4][8];
    const int tid  = threadIdx.x;
    const int wave = tid >> 6;
    const int lane = tid & 63;
    const int j0   = blockIdx.x * 8;

    // x: 32 floats per lane, matching the fp16 weight layout.
    float xv[32];
    const float4* xp = (const float4*)x;
#pragma unroll
    for (int k = 0; k < 4; ++k) {
        float4 a = xp[k * 128 + lane * 2];
        float4 b = xp[k * 128 + lane * 2 + 1];
        xv[k * 8 + 0] = a.x; xv[k * 8 + 1] = a.y; xv[k * 8 + 2] = a.z; xv[k * 8 + 3] = a.w;
        xv[k * 8 + 4] = b.x; xv[k * 8 + 5] = b.y; xv[k * 8 + 6] = b.z; xv[k * 8 + 7] = b.w;
    }

    float acc[8];
#pragma unroll
    for (int j8 = 0; j8 < 8; ++j8) {
        const int R = wave * HDIM + j0 + j8;
        const uint4* wr = (const uint4*)(W + (size_t)R * HDIM);
        float a = 0.0f;
#pragma unroll
        for (int k = 0; k < 4; ++k) {
            uint4 wv = wr[k * 64 + lane];
            const __half* hh = (const __half*)&wv;
#pragma unroll
            for (int e = 0; e < 8; ++e)
                a = fmaf(__half2float(hh[e]), xv[k * 8 + e], a);
        }
        acc[j8] = a;
    }

#pragma unroll
    for (int j8 = 0; j8 < 8; ++j8) {
        float a = acc[j8];
#pragma unroll
        for (int off = 32; off > 0; off >>= 1) a += __shfl_down(a, off, 64);
        if (lane == 0) gates[wave][j8] = a + bsum[wave * HDIM + j0 + j8];
    }
    __syncthreads();

    if (tid < 8) {
        const int j = j0 + tid;
        const float si = 1.0f / (1.0f + expf(-gates[0][tid]));
        const float sf = 1.0f / (1.0f + expf(-gates[1][tid]));
        const float so = 1.0f / (1.0f + expf(-gates[3][tid]));
        const float tg = tanhf(gates[2][tid]);
        const float cn = sf * c[j] + si * tg;
        c[j]     = cn;
        h_out[j] = so * tanhf(cn);
    }
}

// ---------------------------------------------------------------------------
extern "C" void kernel_launch(void* const* d_in, const int* in_sizes, int n_in,
                              void* d_out, int out_size, void* d_ws, size_t ws_size,
                              hipStream_t stream) {
    const float* X   = (const float*)d_in[0];
    const float* Wih = (const float*)d_in[1];
    const float* Whh = (const float*)d_in[2];
    const float* bih = (const float*)d_in[3];
    const float* bhh = (const float*)d_in[4];
    float* out = (float*)d_out;

    const int T = out_size / HDIM;  // 512

    // Workspace: [W_sum fp16 (33.55 MB)][b_sum (32 KB)][c (8 KB)]
    const size_t wsum_bytes = (size_t)G4 * HDIM * sizeof(__half);
    const size_t need = wsum_bytes + (size_t)G4 * sizeof(float) + (size_t)HDIM * sizeof(float);
    char* ws = (char*)d_ws;

    __half* Wsum = nullptr;
    float *bsum, *c;
    const bool have_wsum = (ws_size >= need);
    if (have_wsum) {
        Wsum = (__half*)ws;
        bsum = (float*)(ws + wsum_bytes);
        c    = bsum + G4;
    } else {
        bsum = (float*)ws;
        c    = bsum + G4;
    }

    prep_small<<<(G4 + 255) / 256, 256, 0, stream>>>(bih, bhh, bsum, c);
    if (have_wsum)
        prep_wsum_h<<<2048, 256, 0, stream>>>(Wih, Whh, Wsum);

    // t = 0: gates = X @ W_ih.T + b_sum (h0 = 0) — full fp32 path.
    lstm_step_f32<<<256, 256, 0, stream>>>(X, Wih, nullptr, bsum, c, out);

    // t >= 1: gates = h_{t-1} @ W_sum.T + b_sum (feedback: x == h).
    for (int t = 1; t < T; ++t) {
        const float* hprev = out + (size_t)(t - 1) * HDIM;
        float* hnext = out + (size_t)t * HDIM;
        if (have_wsum)
            lstm_step_h<<<256, 256, 0, stream>>>(hprev, Wsum, bsum, c, hnext);
        else
            lstm_step_f32<<<256, 256, 0, stream>>>(hprev, Wih, Whh, bsum, c, hnext);
    }
}